// Round 9
// baseline (41750.613 us; speedup 1.0000x reference)
//
#include <hip/hip_runtime.h>
#include <math.h>

// EarthMoverDistance: exact integer Jonker-Volgenant with a massively
// parallel epsilon-scaling auction warm start. B=8, N=1024, 3-D Euclidean
// cost quantized to u16 (scale 4096; auction/SSP run in x4-scaled integer
// units so final eps = 1/4 quantum; final sum recomputed fp32 from coords).
//
// R9: R4/R8 showed serial in-wave inits can't produce near-optimal duals,
// leaving the heavy tail of SSP searches (~90k settles x ~600cyc = 22ms).
// The auction parallelizes across the chip: Jacobi rounds of (bid kernel:
// one wave per free person, min/min2 scan, atomicMax bid post) + (resolve
// kernel: one thread per column). Fixed launch schedule (~54 rounds) keeps
// graph capture happy. A projection kernel then rebuilds the exact JV
// precondition (u[i]=min_j(c+p) feasible duals; non-tight matches freed),
// and the R8-validated exact SSP (used-bitmask gate, deferred duals,
// absmax 0.0) finishes. Correctness never depends on auction quality.

#define N      1024
#define BATCH  8
#define NSLOT  16
#define INFI   0x3FFFFFFF
#define SCALE  4096.0f
#define CSH    2                  // auction/SSP cost unit = quantum << CSH
#define PMAX   ((1 << 20) - 1)

__global__ void emd_zero_kernel(float* out) { out[0] = 0.0f; }

__global__ __launch_bounds__(256)
void emd_init_state(int* price, int* owner, int* assigned, unsigned* bidbuf) {
    int t = blockIdx.x * 256 + threadIdx.x;     // grid covers B*N exactly
    price[t] = 0; owner[t] = 0; assigned[t] = 0; bidbuf[t] = 0;
}

// ---- cost cache: Dq[b][r][c] = round(dist * 4096), clamped u16 ----
__global__ __launch_bounds__(256)
void emd_dist_kernel(const float* __restrict__ S1, const float* __restrict__ S2,
                     unsigned short* __restrict__ D) {
    int b = blockIdx.x >> 10;
    int r = blockIdx.x & (N - 1);
    const float* s1 = S1 + ((size_t)b * N + r) * 3;
    float x1 = s1[0], y1 = s1[1], z1 = s1[2];
    const float* s2 = S2 + (size_t)b * N * 3;
    unsigned short* drow = D + ((size_t)b * N + r) * (size_t)N;
    for (int c = threadIdx.x; c < N; c += 256) {
        float dx = x1 - s2[3 * c], dy = y1 - s2[3 * c + 1], dz = z1 - s2[3 * c + 2];
        float d = sqrtf(dx * dx + dy * dy + dz * dz);
        int qv = (int)(d * SCALE + 0.5f);
        drow[c] = (unsigned short)(qv > 65535 ? 65535 : qv);
    }
}

__device__ __forceinline__ unsigned umin32(unsigned a, unsigned b) { return a < b ? a : b; }

template<int CTRL>
__device__ __forceinline__ unsigned dppmin_u32(unsigned x) {
    int y = __builtin_amdgcn_update_dpp((int)x, (int)x, CTRL, 0xF, 0xF, false);
    return umin32(x, (unsigned)y);
}
__device__ __forceinline__ unsigned wave_min_u32(unsigned x) {
    x = dppmin_u32<0x111>(x);   // row_shr:1
    x = dppmin_u32<0x112>(x);   // row_shr:2
    x = dppmin_u32<0x114>(x);   // row_shr:4
    x = dppmin_u32<0x118>(x);   // row_shr:8
    x = dppmin_u32<0x142>(x);   // row_bcast:15
    x = dppmin_u32<0x143>(x);   // row_bcast:31
    return (unsigned)__builtin_amdgcn_readlane((int)x, 63);
}
__device__ __forceinline__ unsigned treemin16(const unsigned* k) {
    unsigned t[8];
#pragma unroll
    for (int i = 0; i < 8; ++i) t[i] = umin32(k[2 * i], k[2 * i + 1]);
#pragma unroll
    for (int i = 0; i < 4; ++i) t[i] = umin32(t[2 * i], t[2 * i + 1]);
    t[0] = umin32(t[0], t[1]);
    t[1] = umin32(t[2], t[3]);
    return umin32(t[0], t[1]);
}

// ---- auction bid: one wave per person; 4 persons (waves) per block ----
__global__ __launch_bounds__(256)
void emd_bid(const unsigned short* __restrict__ D, const int* __restrict__ price,
             const int* __restrict__ assigned, unsigned* __restrict__ bidbuf,
             int eps) {
    int wv = threadIdx.x >> 6, lane = threadIdx.x & 63;
    int gp = blockIdx.x * 4 + wv;
    int b = gp >> 10, i = (gp & 1023) + 1;
    if (assigned[b * N + i - 1] != 0) return;
    const uint4* r4 = (const uint4*)(D + ((size_t)b << 20) + (size_t)(i - 1) * N);
    uint4 wA = r4[lane * 2], wB = r4[lane * 2 + 1];
    unsigned ww[8] = {wA.x, wA.y, wA.z, wA.w, wB.x, wB.y, wB.z, wB.w};
    const int4* p4 = (const int4*)(price + b * N);
    int4 q0 = p4[lane * 4], q1 = p4[lane * 4 + 1], q2 = p4[lane * 4 + 2], q3 = p4[lane * 4 + 3];
    int pv[NSLOT] = {q0.x, q0.y, q0.z, q0.w, q1.x, q1.y, q1.z, q1.w,
                     q2.x, q2.y, q2.z, q2.w, q3.x, q3.y, q3.z, q3.w};
    unsigned keys[NSLOT];
#pragma unroll
    for (int k = 0; k < NSLOT; ++k) {
        int d = (int)((k & 1) ? (ww[k >> 1] >> 16) : (ww[k >> 1] & 0xFFFFu)) << CSH;
        keys[k] = ((unsigned)(d + pv[k]) << 11) | (unsigned)(lane * NSLOT + k + 1);
    }
    unsigned k1 = wave_min_u32(treemin16(keys));
    int j1 = (int)(k1 & 0x7FF);
    int lo = (j1 - 1) >> 4, kk = (j1 - 1) & 15;
    if (lane == lo) {
#pragma unroll
        for (int k = 0; k < NSLOT; ++k) if (k == kk) keys[k] = 0xFFFFFFFFu;
    }
    unsigned k2 = wave_min_u32(treemin16(keys));
    if (lane == lo) {
        int npr = pv[kk] + (int)((k2 >> 11) - (k1 >> 11)) + eps;
        if (npr > PMAX) npr = PMAX;
        atomicMax(&bidbuf[b * N + j1 - 1], ((unsigned)npr << 11) | (unsigned)i);
    }
}

// ---- auction resolve: one thread per column ----
__global__ __launch_bounds__(256)
void emd_resolve(unsigned* __restrict__ bidbuf, int* __restrict__ price,
                 int* __restrict__ owner, int* __restrict__ assigned) {
    int t = blockIdx.x * 256 + threadIdx.x;     // grid covers B*N exactly
    unsigned bb = bidbuf[t];
    if (!bb) return;
    bidbuf[t] = 0;
    int i = (int)(bb & 0x7FF);
    int npr = (int)(bb >> 11);
    int b = t >> 10;
    int old = owner[t];
    if (old) assigned[b * N + old - 1] = 0;   // old was assigned at bid time:
    owner[t] = i;                             //   it didn't bid this round
    assigned[b * N + i - 1] = (t & 1023) + 1;
    price[t] = npr;
}

// ---- projection: u[i] = min_j(c+p) (feasible); free non-tight matches ----
__global__ __launch_bounds__(256)
void emd_project(const unsigned short* __restrict__ D, const int* __restrict__ price,
                 int* __restrict__ owner, int* __restrict__ assigned,
                 int* __restrict__ uarr) {
    int wv = threadIdx.x >> 6, lane = threadIdx.x & 63;
    int gp = blockIdx.x * 4 + wv;
    int b = gp >> 10, i = (gp & 1023) + 1;
    const uint4* r4 = (const uint4*)(D + ((size_t)b << 20) + (size_t)(i - 1) * N);
    uint4 wA = r4[lane * 2], wB = r4[lane * 2 + 1];
    unsigned ww[8] = {wA.x, wA.y, wA.z, wA.w, wB.x, wB.y, wB.z, wB.w};
    const int4* p4 = (const int4*)(price + b * N);
    int4 q0 = p4[lane * 4], q1 = p4[lane * 4 + 1], q2 = p4[lane * 4 + 2], q3 = p4[lane * 4 + 3];
    int pv[NSLOT] = {q0.x, q0.y, q0.z, q0.w, q1.x, q1.y, q1.z, q1.w,
                     q2.x, q2.y, q2.z, q2.w, q3.x, q3.y, q3.z, q3.w};
    int w[NSLOT]; unsigned mk[NSLOT];
#pragma unroll
    for (int k = 0; k < NSLOT; ++k) {
        int d = (int)((k & 1) ? (ww[k >> 1] >> 16) : (ww[k >> 1] & 0xFFFFu)) << CSH;
        w[k] = d + pv[k];
        mk[k] = (unsigned)w[k];
    }
    unsigned wmin = wave_min_u32(treemin16(mk));
    if (lane == 0) uarr[b * N + i - 1] = (int)wmin;
    int j = assigned[b * N + i - 1];           // wave-uniform read
    if (j) {
        int lo = (j - 1) >> 4, kk = (j - 1) & 15;
        if (lane == lo) {
            bool tight = false;
#pragma unroll
            for (int k = 0; k < NSLOT; ++k) if (k == kk) tight = ((unsigned)w[k] == wmin);
            if (!tight) { assigned[b * N + i - 1] = 0; owner[b * N + j - 1] = 0; }
        }
    }
}

// ---- exact SSP (R8-validated core) from the auction warm start ----
template<bool CACHED>
__global__ __launch_bounds__(64, 1)
void emd_jv_kernel(const float* __restrict__ S1,
                   const float* __restrict__ S2,
                   const unsigned short* __restrict__ Dc,
                   const int* __restrict__ price,
                   const int* __restrict__ owner,
                   const int* __restrict__ assigned,
                   const int* __restrict__ uarr,
                   float* __restrict__ out) {
    __shared__ float4 s1c[N + 1];     // row coords (final fp32 sum; !CACHED costs)
    __shared__ int    u_lds[N + 1];   // row potentials (scaled int units)
    __shared__ int    den[N + 1];     // D value when column settled
    __shared__ int    rowm[N + 1];    // row -> matched col (0 = free)

    const int lane = threadIdx.x;
    const int b = blockIdx.x;
    const float* s1g = S1 + (size_t)b * N * 3;
    const float* s2g = S2 + (size_t)b * N * 3;
    const unsigned short* Db = CACHED ? (Dc + ((size_t)b << 20)) : (const unsigned short*)0;

    for (int t = lane; t < N; t += 64) {
        s1c[t + 1] = make_float4(s1g[3 * t], s1g[3 * t + 1], s1g[3 * t + 2], 0.0f);
        u_lds[t + 1] = CACHED ? uarr[b * N + t] : 0;
        rowm[t + 1] = CACHED ? assigned[b * N + t] : 0;
    }
    if (lane == 0) { u_lds[0] = 0; rowm[0] = 0; }

    // per-lane column state: col j = c+1, c = lane*16+k
    int nv[NSLOT];    // NEGATED column dual: CACHED -> price (v = -p)
    int jpk[NSLOT];   // (matched_row<<11)|j ; row 0 = free
    float x2[NSLOT], y2[NSLOT], z2[NSLOT];   // !CACHED cost compute only

    if (!CACHED) {
#pragma unroll
        for (int k = 0; k < NSLOT; ++k) {
            int pt = lane * NSLOT + k;
            x2[k] = s2g[3 * pt]; y2[k] = s2g[3 * pt + 1]; z2[k] = s2g[3 * pt + 2];
        }
    }
    __syncthreads();

    if (CACHED) {
#pragma unroll
        for (int k = 0; k < NSLOT; ++k) {
            int c = lane * NSLOT + k;
            nv[k] = price[b * N + c];
            jpk[k] = (owner[b * N + c] << 11) | (c + 1);
        }
    } else {
        // in-wave column reduction + greedy (R3/R8-validated fallback)
        int bd[NSLOT], im[NSLOT];
#pragma unroll
        for (int k = 0; k < NSLOT; ++k) { bd[k] = INFI; im[k] = 1; }
        for (int r = 1; r <= N; ++r) {
            float4 qq = s1c[r];
#pragma unroll
            for (int k = 0; k < NSLOT; ++k) {
                float dx = qq.x - x2[k], dy = qq.y - y2[k], dz = qq.z - z2[k];
                float dd = sqrtf(dx * dx + dy * dy + dz * dz);
                int di = (int)(dd * SCALE + 0.5f); if (di > 65535) di = 65535;
                if (di < bd[k]) { bd[k] = di; im[k] = r; }
            }
        }
#pragma unroll
        for (int k = 0; k < NSLOT; ++k) nv[k] = -bd[k];
#pragma unroll
        for (int k = 0; k < NSLOT; ++k) {
            int j = lane * NSLOT + k + 1;
            int r = im[k];
            int old = atomicCAS(&rowm[r], 0, j);
            jpk[k] = ((old == 0 ? r : 0) << 11) | j;
        }
        __syncthreads();
    }

    auto loadrow = [&](int rr, int* d) {
        if (CACHED) {
            const uint4* p = (const uint4*)(Db + (size_t)(rr - 1) * N);
            uint4 w0 = p[lane * 2], w1 = p[lane * 2 + 1];
            unsigned ww[8] = {w0.x, w0.y, w0.z, w0.w, w1.x, w1.y, w1.z, w1.w};
#pragma unroll
            for (int t = 0; t < 8; ++t) {
                d[2 * t] = (int)(ww[t] & 0xFFFFu) << CSH;
                d[2 * t + 1] = (int)(ww[t] >> 16) << CSH;
            }
        } else {
            float4 qq = s1c[rr];
#pragma unroll
            for (int k = 0; k < NSLOT; ++k) {
                float dx = qq.x - x2[k], dy = qq.y - y2[k], dz = qq.z - z2[k];
                float dd = sqrtf(dx * dx + dy * dy + dz * dz);
                int di = (int)(dd * SCALE + 0.5f); if (di > 65535) di = 65535;
                d[k] = di;
            }
        }
    };

    int minv[NSLOT], way[NSLOT];
    unsigned used = 0u;

    auto expand = [&](int rr, int jpred, int Dh) {
        int d[NSLOT]; loadrow(rr, d);
        int base = Dh - u_lds[rr];
#pragma unroll
        for (int k = 0; k < NSLOT; ++k) {
            int cur = d[k] + nv[k] + base;
            // used-bit gate: settled slots keep minv/way frozen (R8 bugfix)
            bool upd = !((used >> k) & 1u) && (unsigned)cur < (unsigned)minv[k];
            minv[k] = upd ? cur : minv[k];
            way[k] = upd ? jpred : way[k];
        }
    };

    for (int i = 1; i <= N; ++i) {
        if (__builtin_amdgcn_readfirstlane(rowm[i]) != 0) continue;

        used = 0u;
        int DT = 0, freecol = 0;
#pragma unroll
        for (int k = 0; k < NSLOT; ++k) { minv[k] = INFI; way[k] = 0; }
        expand(i, 0, 0);

        int guard = 0;
        for (;;) {
            if (++guard > N + 4) break;
            // pair-tree argmin over (minv, jpk)
            int tv[8], tj[8];
#pragma unroll
            for (int t = 0; t < 8; ++t) {
                bool c = (unsigned)minv[2 * t + 1] < (unsigned)minv[2 * t];
                tv[t] = c ? minv[2 * t + 1] : minv[2 * t];
                tj[t] = c ? jpk[2 * t + 1] : jpk[2 * t];
            }
#pragma unroll
            for (int t = 0; t < 4; ++t) {
                bool c = (unsigned)tv[2 * t + 1] < (unsigned)tv[2 * t];
                tv[t] = c ? tv[2 * t + 1] : tv[2 * t];
                tj[t] = c ? tj[2 * t + 1] : tj[2 * t];
            }
            {
                bool c = (unsigned)tv[1] < (unsigned)tv[0];
                tv[0] = c ? tv[1] : tv[0]; tj[0] = c ? tj[1] : tj[0];
                c = (unsigned)tv[3] < (unsigned)tv[2];
                tv[1] = c ? tv[3] : tv[2]; tj[1] = c ? tj[3] : tj[2];
                c = (unsigned)tv[1] < (unsigned)tv[0];
                tv[0] = c ? tv[1] : tv[0]; tj[0] = c ? tj[1] : tj[0];
            }
            unsigned gmin = wave_min_u32((unsigned)tv[0]);
            if (gmin >= (unsigned)INFI) break;
            unsigned long long tm = __ballot((unsigned)tv[0] == gmin);
            DT = (int)gmin;
            freecol = 0;
            // free-column short-circuit: zero expands if any tie is free
            unsigned long long tf = tm;
            while (tf) {
                int l = __ffsll((long long)tf) - 1; tf &= tf - 1;
                int jp = __builtin_amdgcn_readlane(tj[0], l);
                if ((jp >> 11) == 0) { freecol = jp & 0x7FF; break; }
            }
            if (freecol) break;
            // settle all matched ties at gmin
            while (tm) {
                int l = __ffsll((long long)tm) - 1; tm &= tm - 1;
                int jp = __builtin_amdgcn_readlane(tj[0], l);
                int jj = jp & 0x7FF, rr = jp >> 11;
                if (lane == 0) den[jj] = DT;
                int lo = (jj - 1) >> 4, kk = (jj - 1) & 15;
                if (lane == lo) {
#pragma unroll
                    for (int k = 0; k < NSLOT; ++k)
                        if (k == kk) { minv[k] = INFI; used |= (1u << k); }
                }
                expand(rr, jj, DT);
            }
        }
        if (freecol == 0) continue;

        __syncthreads();
        // deferred dual updates (pre-augment jpk)
        if (lane == 0) u_lds[i] += DT;
#pragma unroll
        for (int k = 0; k < NSLOT; ++k) {
            if ((used >> k) & 1u) {
                int j = lane * NSLOT + k + 1;
                int dd = DT - den[j];
                nv[k] += dd;                 // v -= dd
                u_lds[jpk[k] >> 11] += dd;   // distinct rows: race-free
            }
        }
        __syncthreads();

        // augment along alternating path
        int j0 = freecol, ag = 0;
        while (j0 != 0) {
            if (++ag > N + 4) break;
            int cc = j0 - 1, lo = cc >> 4, kk = cc & 15;
            int wl = way[0];
#pragma unroll
            for (int k = 1; k < NSLOT; ++k) if (k == kk) wl = way[k];
            int j1 = __builtin_amdgcn_readlane(wl, lo);
            int np;
            if (j1 == 0) np = i;
            else {
                int c1 = j1 - 1, lo1 = c1 >> 4, kk1 = c1 & 15;
                int pl = jpk[0];
#pragma unroll
                for (int k = 1; k < NSLOT; ++k) if (k == kk1) pl = jpk[k];
                np = __builtin_amdgcn_readlane(pl, lo1) >> 11;
            }
            if (lane == lo) {
#pragma unroll
                for (int k = 0; k < NSLOT; ++k) if (k == kk) jpk[k] = (np << 11) | j0;
            }
            if (lane == 0) rowm[np] = j0;
            j0 = j1;
        }
        __syncthreads();
    }

    // ---- total matched cost: fp32 from coordinates ----
    float sum = 0.0f;
#pragma unroll
    for (int k = 0; k < NSLOT; ++k) {
        int c = lane * NSLOT + k;
        int r = jpk[k] >> 11; if (r < 1) r = 1;
        float4 qq = s1c[r];
        float sx = s2g[3 * c], sy = s2g[3 * c + 1], sz = s2g[3 * c + 2];
        float dx = qq.x - sx, dy = qq.y - sy, dz = qq.z - sz;
        sum += sqrtf(dx * dx + dy * dy + dz * dz);
    }
#pragma unroll
    for (int off = 32; off >= 1; off >>= 1) sum += __shfl_xor(sum, off);
    if (lane == 0) atomicAdd(out, sum * (1.0f / ((float)N * (float)BATCH)));
}

extern "C" void kernel_launch(void* const* d_in, const int* in_sizes, int n_in,
                              void* d_out, int out_size, void* d_ws, size_t ws_size,
                              hipStream_t stream) {
    const float* S1 = (const float*)d_in[0];
    const float* S2 = (const float*)d_in[1];
    float* out = (float*)d_out;

    size_t needD = (size_t)BATCH * N * N * sizeof(unsigned short);   // 16 MB
    size_t needA = (size_t)BATCH * N * 5 * sizeof(int);              // state
    emd_zero_kernel<<<1, 1, 0, stream>>>(out);

    if (ws_size >= needD + needA) {
        unsigned short* D = (unsigned short*)d_ws;
        int* price    = (int*)((char*)d_ws + needD);
        int* owner    = price + BATCH * N;
        int* assigned = owner + BATCH * N;
        int* uarr     = assigned + BATCH * N;
        unsigned* bidbuf = (unsigned*)(uarr + BATCH * N);

        emd_init_state<<<(BATCH * N) / 256, 256, 0, stream>>>(price, owner, assigned, bidbuf);
        emd_dist_kernel<<<BATCH * N, 256, 0, stream>>>(S1, S2, D);

        static const int eps_sched[8]  = {16384, 4096, 1024, 256, 64, 16, 4, 1};
        static const int rnds_sched[8] = {5, 5, 6, 6, 7, 7, 8, 10};
        for (int p = 0; p < 8; ++p)
            for (int r = 0; r < rnds_sched[p]; ++r) {
                emd_bid<<<BATCH * 256, 256, 0, stream>>>(D, price, assigned, bidbuf, eps_sched[p]);
                emd_resolve<<<(BATCH * N) / 256, 256, 0, stream>>>(bidbuf, price, owner, assigned);
            }
        emd_project<<<BATCH * 256, 256, 0, stream>>>(D, price, owner, assigned, uarr);
        emd_jv_kernel<true><<<BATCH, 64, 0, stream>>>(S1, S2, D, price, owner, assigned, uarr, out);
    } else {
        emd_jv_kernel<false><<<BATCH, 64, 0, stream>>>(S1, S2, nullptr, nullptr, nullptr, nullptr, nullptr, out);
    }
}

// Round 10
// 28744.983 us; speedup vs baseline: 1.4524x; 1.4524x over previous
//
#include <hip/hip_runtime.h>
#include <math.h>

// EarthMoverDistance: exact integer Jonker-Volgenant with a massively
// parallel epsilon-scaling auction warm start. B=8, N=1024, 3-D Euclidean
// cost quantized to u16 (scale 4096; auction/SSP in x4-scaled integer units;
// final sum recomputed fp32 from coords). Exact SSP cleanup => correctness
// never depends on auction quality (validated R9: absmax 0.0).
//
// R10: R9's auction was schedule-starved (54 rounds; SSP 42ms, worse than
// greedy init -> prices mid-flight). Fixes:
//  (a) 200 round-pairs, eps 4096->1 (/4), weighted to small-eps phases
//      (~2ms total; free-person waves early-exit so rounds are cheap);
//  (b) projection stores each person's argmin (tight) column; new claim
//      kernel: free persons atomicCAS-claim their tight column post-
//      projection (separate launch => race-free), halving SSP searches.

#define N      1024
#define BATCH  8
#define NSLOT  16
#define INFI   0x3FFFFFFF
#define SCALE  4096.0f
#define CSH    2                  // auction/SSP cost unit = quantum << CSH
#define PMAX   ((1 << 20) - 1)

__global__ void emd_zero_kernel(float* out) { out[0] = 0.0f; }

__global__ __launch_bounds__(256)
void emd_init_state(int* price, int* owner, int* assigned, unsigned* bidbuf) {
    int t = blockIdx.x * 256 + threadIdx.x;     // grid covers B*N exactly
    price[t] = 0; owner[t] = 0; assigned[t] = 0; bidbuf[t] = 0;
}

// ---- cost cache: Dq[b][r][c] = round(dist * 4096), clamped u16 ----
__global__ __launch_bounds__(256)
void emd_dist_kernel(const float* __restrict__ S1, const float* __restrict__ S2,
                     unsigned short* __restrict__ D) {
    int b = blockIdx.x >> 10;
    int r = blockIdx.x & (N - 1);
    const float* s1 = S1 + ((size_t)b * N + r) * 3;
    float x1 = s1[0], y1 = s1[1], z1 = s1[2];
    const float* s2 = S2 + (size_t)b * N * 3;
    unsigned short* drow = D + ((size_t)b * N + r) * (size_t)N;
    for (int c = threadIdx.x; c < N; c += 256) {
        float dx = x1 - s2[3 * c], dy = y1 - s2[3 * c + 1], dz = z1 - s2[3 * c + 2];
        float d = sqrtf(dx * dx + dy * dy + dz * dz);
        int qv = (int)(d * SCALE + 0.5f);
        drow[c] = (unsigned short)(qv > 65535 ? 65535 : qv);
    }
}

__device__ __forceinline__ unsigned umin32(unsigned a, unsigned b) { return a < b ? a : b; }

template<int CTRL>
__device__ __forceinline__ unsigned dppmin_u32(unsigned x) {
    int y = __builtin_amdgcn_update_dpp((int)x, (int)x, CTRL, 0xF, 0xF, false);
    return umin32(x, (unsigned)y);
}
__device__ __forceinline__ unsigned wave_min_u32(unsigned x) {
    x = dppmin_u32<0x111>(x);   // row_shr:1
    x = dppmin_u32<0x112>(x);   // row_shr:2
    x = dppmin_u32<0x114>(x);   // row_shr:4
    x = dppmin_u32<0x118>(x);   // row_shr:8
    x = dppmin_u32<0x142>(x);   // row_bcast:15
    x = dppmin_u32<0x143>(x);   // row_bcast:31
    return (unsigned)__builtin_amdgcn_readlane((int)x, 63);
}
__device__ __forceinline__ unsigned treemin16(const unsigned* k) {
    unsigned t[8];
#pragma unroll
    for (int i = 0; i < 8; ++i) t[i] = umin32(k[2 * i], k[2 * i + 1]);
#pragma unroll
    for (int i = 0; i < 4; ++i) t[i] = umin32(t[2 * i], t[2 * i + 1]);
    t[0] = umin32(t[0], t[1]);
    t[1] = umin32(t[2], t[3]);
    return umin32(t[0], t[1]);
}

// ---- auction bid: one wave per person; 4 persons (waves) per block ----
__global__ __launch_bounds__(256)
void emd_bid(const unsigned short* __restrict__ D, const int* __restrict__ price,
             const int* __restrict__ assigned, unsigned* __restrict__ bidbuf,
             int eps) {
    int wv = threadIdx.x >> 6, lane = threadIdx.x & 63;
    int gp = blockIdx.x * 4 + wv;
    int b = gp >> 10, i = (gp & 1023) + 1;
    if (assigned[b * N + i - 1] != 0) return;
    const uint4* r4 = (const uint4*)(D + ((size_t)b << 20) + (size_t)(i - 1) * N);
    uint4 wA = r4[lane * 2], wB = r4[lane * 2 + 1];
    unsigned ww[8] = {wA.x, wA.y, wA.z, wA.w, wB.x, wB.y, wB.z, wB.w};
    const int4* p4 = (const int4*)(price + b * N);
    int4 q0 = p4[lane * 4], q1 = p4[lane * 4 + 1], q2 = p4[lane * 4 + 2], q3 = p4[lane * 4 + 3];
    int pv[NSLOT] = {q0.x, q0.y, q0.z, q0.w, q1.x, q1.y, q1.z, q1.w,
                     q2.x, q2.y, q2.z, q2.w, q3.x, q3.y, q3.z, q3.w};
    unsigned keys[NSLOT];
#pragma unroll
    for (int k = 0; k < NSLOT; ++k) {
        int d = (int)((k & 1) ? (ww[k >> 1] >> 16) : (ww[k >> 1] & 0xFFFFu)) << CSH;
        keys[k] = ((unsigned)(d + pv[k]) << 11) | (unsigned)(lane * NSLOT + k + 1);
    }
    unsigned k1 = wave_min_u32(treemin16(keys));
    int j1 = (int)(k1 & 0x7FF);
    int lo = (j1 - 1) >> 4, kk = (j1 - 1) & 15;
    if (lane == lo) {
#pragma unroll
        for (int k = 0; k < NSLOT; ++k) if (k == kk) keys[k] = 0xFFFFFFFFu;
    }
    unsigned k2 = wave_min_u32(treemin16(keys));
    if (lane == lo) {
        int npr = pv[kk] + (int)((k2 >> 11) - (k1 >> 11)) + eps;
        if (npr > PMAX) npr = PMAX;
        atomicMax(&bidbuf[b * N + j1 - 1], ((unsigned)npr << 11) | (unsigned)i);
    }
}

// ---- auction resolve: one thread per column ----
__global__ __launch_bounds__(256)
void emd_resolve(unsigned* __restrict__ bidbuf, int* __restrict__ price,
                 int* __restrict__ owner, int* __restrict__ assigned) {
    int t = blockIdx.x * 256 + threadIdx.x;     // grid covers B*N exactly
    unsigned bb = bidbuf[t];
    if (!bb) return;
    bidbuf[t] = 0;
    int i = (int)(bb & 0x7FF);
    int npr = (int)(bb >> 11);
    int b = t >> 10;
    int old = owner[t];
    if (old) assigned[b * N + old - 1] = 0;   // old was assigned at bid time:
    owner[t] = i;                             //   it didn't bid this round
    assigned[b * N + i - 1] = (t & 1023) + 1;
    price[t] = npr;
}

// ---- projection: u[i] = min_j(c+p) (feasible); free non-tight matches;
//      record per-person argmin (tight) column for the claim pass ----
__global__ __launch_bounds__(256)
void emd_project(const unsigned short* __restrict__ D, const int* __restrict__ price,
                 int* __restrict__ owner, int* __restrict__ assigned,
                 int* __restrict__ uarr, int* __restrict__ jmin) {
    int wv = threadIdx.x >> 6, lane = threadIdx.x & 63;
    int gp = blockIdx.x * 4 + wv;
    int b = gp >> 10, i = (gp & 1023) + 1;
    const uint4* r4 = (const uint4*)(D + ((size_t)b << 20) + (size_t)(i - 1) * N);
    uint4 wA = r4[lane * 2], wB = r4[lane * 2 + 1];
    unsigned ww[8] = {wA.x, wA.y, wA.z, wA.w, wB.x, wB.y, wB.z, wB.w};
    const int4* p4 = (const int4*)(price + b * N);
    int4 q0 = p4[lane * 4], q1 = p4[lane * 4 + 1], q2 = p4[lane * 4 + 2], q3 = p4[lane * 4 + 3];
    int pv[NSLOT] = {q0.x, q0.y, q0.z, q0.w, q1.x, q1.y, q1.z, q1.w,
                     q2.x, q2.y, q2.z, q2.w, q3.x, q3.y, q3.z, q3.w};
    int w[NSLOT]; unsigned mk[NSLOT];
#pragma unroll
    for (int k = 0; k < NSLOT; ++k) {
        int d = (int)((k & 1) ? (ww[k >> 1] >> 16) : (ww[k >> 1] & 0xFFFFu)) << CSH;
        w[k] = d + pv[k];
        mk[k] = ((unsigned)w[k] << 11) | (unsigned)(lane * NSLOT + k + 1);
    }
    unsigned kmin = wave_min_u32(treemin16(mk));
    int wmin = (int)(kmin >> 11);
    if (lane == 0) {
        uarr[b * N + i - 1] = wmin;
        jmin[b * N + i - 1] = (int)(kmin & 0x7FF);
    }
    int j = assigned[b * N + i - 1];           // wave-uniform read
    if (j) {
        int lo = (j - 1) >> 4, kk = (j - 1) & 15;
        if (lane == lo) {
            bool tight = false;
#pragma unroll
            for (int k = 0; k < NSLOT; ++k) if (k == kk) tight = (w[k] == wmin);
            if (!tight) { assigned[b * N + i - 1] = 0; owner[b * N + j - 1] = 0; }
        }
    }
}

// ---- claim: free persons CAS-claim their tight argmin column ----
__global__ __launch_bounds__(256)
void emd_claim(int* __restrict__ owner, int* __restrict__ assigned,
               const int* __restrict__ jmin) {
    int t = blockIdx.x * 256 + threadIdx.x;     // person index, covers B*N
    if (assigned[t] != 0) return;
    int b = t >> 10, i = (t & 1023) + 1;
    int j = jmin[t];
    if (atomicCAS(&owner[b * N + j - 1], 0, i) == 0) assigned[t] = j;
}

// ---- exact SSP (R8/R9-validated core) from the auction warm start ----
template<bool CACHED>
__global__ __launch_bounds__(64, 1)
void emd_jv_kernel(const float* __restrict__ S1,
                   const float* __restrict__ S2,
                   const unsigned short* __restrict__ Dc,
                   const int* __restrict__ price,
                   const int* __restrict__ owner,
                   const int* __restrict__ assigned,
                   const int* __restrict__ uarr,
                   float* __restrict__ out) {
    __shared__ float4 s1c[N + 1];     // row coords (final fp32 sum; !CACHED costs)
    __shared__ int    u_lds[N + 1];   // row potentials (scaled int units)
    __shared__ int    den[N + 1];     // D value when column settled
    __shared__ int    rowm[N + 1];    // row -> matched col (0 = free)

    const int lane = threadIdx.x;
    const int b = blockIdx.x;
    const float* s1g = S1 + (size_t)b * N * 3;
    const float* s2g = S2 + (size_t)b * N * 3;
    const unsigned short* Db = CACHED ? (Dc + ((size_t)b << 20)) : (const unsigned short*)0;

    for (int t = lane; t < N; t += 64) {
        s1c[t + 1] = make_float4(s1g[3 * t], s1g[3 * t + 1], s1g[3 * t + 2], 0.0f);
        u_lds[t + 1] = CACHED ? uarr[b * N + t] : 0;
        rowm[t + 1] = CACHED ? assigned[b * N + t] : 0;
    }
    if (lane == 0) { u_lds[0] = 0; rowm[0] = 0; }

    // per-lane column state: col j = c+1, c = lane*16+k
    int nv[NSLOT];    // NEGATED column dual: CACHED -> price (v = -p)
    int jpk[NSLOT];   // (matched_row<<11)|j ; row 0 = free
    float x2[NSLOT], y2[NSLOT], z2[NSLOT];   // !CACHED cost compute only

    if (!CACHED) {
#pragma unroll
        for (int k = 0; k < NSLOT; ++k) {
            int pt = lane * NSLOT + k;
            x2[k] = s2g[3 * pt]; y2[k] = s2g[3 * pt + 1]; z2[k] = s2g[3 * pt + 2];
        }
    }
    __syncthreads();

    if (CACHED) {
#pragma unroll
        for (int k = 0; k < NSLOT; ++k) {
            int c = lane * NSLOT + k;
            nv[k] = price[b * N + c];
            jpk[k] = (owner[b * N + c] << 11) | (c + 1);
        }
    } else {
        // in-wave column reduction + greedy (R3/R8-validated fallback)
        int bd[NSLOT], im[NSLOT];
#pragma unroll
        for (int k = 0; k < NSLOT; ++k) { bd[k] = INFI; im[k] = 1; }
        for (int r = 1; r <= N; ++r) {
            float4 qq = s1c[r];
#pragma unroll
            for (int k = 0; k < NSLOT; ++k) {
                float dx = qq.x - x2[k], dy = qq.y - y2[k], dz = qq.z - z2[k];
                float dd = sqrtf(dx * dx + dy * dy + dz * dz);
                int di = (int)(dd * SCALE + 0.5f); if (di > 65535) di = 65535;
                if (di < bd[k]) { bd[k] = di; im[k] = r; }
            }
        }
#pragma unroll
        for (int k = 0; k < NSLOT; ++k) nv[k] = -bd[k];
#pragma unroll
        for (int k = 0; k < NSLOT; ++k) {
            int j = lane * NSLOT + k + 1;
            int r = im[k];
            int old = atomicCAS(&rowm[r], 0, j);
            jpk[k] = ((old == 0 ? r : 0) << 11) | j;
        }
        __syncthreads();
    }

    auto loadrow = [&](int rr, int* d) {
        if (CACHED) {
            const uint4* p = (const uint4*)(Db + (size_t)(rr - 1) * N);
            uint4 w0 = p[lane * 2], w1 = p[lane * 2 + 1];
            unsigned ww[8] = {w0.x, w0.y, w0.z, w0.w, w1.x, w1.y, w1.z, w1.w};
#pragma unroll
            for (int t = 0; t < 8; ++t) {
                d[2 * t] = (int)(ww[t] & 0xFFFFu) << CSH;
                d[2 * t + 1] = (int)(ww[t] >> 16) << CSH;
            }
        } else {
            float4 qq = s1c[rr];
#pragma unroll
            for (int k = 0; k < NSLOT; ++k) {
                float dx = qq.x - x2[k], dy = qq.y - y2[k], dz = qq.z - z2[k];
                float dd = sqrtf(dx * dx + dy * dy + dz * dz);
                int di = (int)(dd * SCALE + 0.5f); if (di > 65535) di = 65535;
                d[k] = di;
            }
        }
    };

    int minv[NSLOT], way[NSLOT];
    unsigned used = 0u;

    auto expand = [&](int rr, int jpred, int Dh) {
        int d[NSLOT]; loadrow(rr, d);
        int base = Dh - u_lds[rr];
#pragma unroll
        for (int k = 0; k < NSLOT; ++k) {
            int cur = d[k] + nv[k] + base;
            // used-bit gate: settled slots keep minv/way frozen (R8 bugfix)
            bool upd = !((used >> k) & 1u) && (unsigned)cur < (unsigned)minv[k];
            minv[k] = upd ? cur : minv[k];
            way[k] = upd ? jpred : way[k];
        }
    };

    for (int i = 1; i <= N; ++i) {
        if (__builtin_amdgcn_readfirstlane(rowm[i]) != 0) continue;

        used = 0u;
        int DT = 0, freecol = 0;
#pragma unroll
        for (int k = 0; k < NSLOT; ++k) { minv[k] = INFI; way[k] = 0; }
        expand(i, 0, 0);

        int guard = 0;
        for (;;) {
            if (++guard > N + 4) break;
            // pair-tree argmin over (minv, jpk)
            int tv[8], tj[8];
#pragma unroll
            for (int t = 0; t < 8; ++t) {
                bool c = (unsigned)minv[2 * t + 1] < (unsigned)minv[2 * t];
                tv[t] = c ? minv[2 * t + 1] : minv[2 * t];
                tj[t] = c ? jpk[2 * t + 1] : jpk[2 * t];
            }
#pragma unroll
            for (int t = 0; t < 4; ++t) {
                bool c = (unsigned)tv[2 * t + 1] < (unsigned)tv[2 * t];
                tv[t] = c ? tv[2 * t + 1] : tv[2 * t];
                tj[t] = c ? tj[2 * t + 1] : tj[2 * t];
            }
            {
                bool c = (unsigned)tv[1] < (unsigned)tv[0];
                tv[0] = c ? tv[1] : tv[0]; tj[0] = c ? tj[1] : tj[0];
                c = (unsigned)tv[3] < (unsigned)tv[2];
                tv[1] = c ? tv[3] : tv[2]; tj[1] = c ? tj[3] : tj[2];
                c = (unsigned)tv[1] < (unsigned)tv[0];
                tv[0] = c ? tv[1] : tv[0]; tj[0] = c ? tj[1] : tj[0];
            }
            unsigned gmin = wave_min_u32((unsigned)tv[0]);
            if (gmin >= (unsigned)INFI) break;
            unsigned long long tm = __ballot((unsigned)tv[0] == gmin);
            DT = (int)gmin;
            freecol = 0;
            // free-column short-circuit: zero expands if any tie is free
            unsigned long long tf = tm;
            while (tf) {
                int l = __ffsll((long long)tf) - 1; tf &= tf - 1;
                int jp = __builtin_amdgcn_readlane(tj[0], l);
                if ((jp >> 11) == 0) { freecol = jp & 0x7FF; break; }
            }
            if (freecol) break;
            // settle all matched ties at gmin
            while (tm) {
                int l = __ffsll((long long)tm) - 1; tm &= tm - 1;
                int jp = __builtin_amdgcn_readlane(tj[0], l);
                int jj = jp & 0x7FF, rr = jp >> 11;
                if (lane == 0) den[jj] = DT;
                int lo = (jj - 1) >> 4, kk = (jj - 1) & 15;
                if (lane == lo) {
#pragma unroll
                    for (int k = 0; k < NSLOT; ++k)
                        if (k == kk) { minv[k] = INFI; used |= (1u << k); }
                }
                expand(rr, jj, DT);
            }
        }
        if (freecol == 0) continue;

        __syncthreads();
        // deferred dual updates (pre-augment jpk)
        if (lane == 0) u_lds[i] += DT;
#pragma unroll
        for (int k = 0; k < NSLOT; ++k) {
            if ((used >> k) & 1u) {
                int j = lane * NSLOT + k + 1;
                int dd = DT - den[j];
                nv[k] += dd;                 // v -= dd
                u_lds[jpk[k] >> 11] += dd;   // distinct rows: race-free
            }
        }
        __syncthreads();

        // augment along alternating path
        int j0 = freecol, ag = 0;
        while (j0 != 0) {
            if (++ag > N + 4) break;
            int cc = j0 - 1, lo = cc >> 4, kk = cc & 15;
            int wl = way[0];
#pragma unroll
            for (int k = 1; k < NSLOT; ++k) if (k == kk) wl = way[k];
            int j1 = __builtin_amdgcn_readlane(wl, lo);
            int np;
            if (j1 == 0) np = i;
            else {
                int c1 = j1 - 1, lo1 = c1 >> 4, kk1 = c1 & 15;
                int pl = jpk[0];
#pragma unroll
                for (int k = 1; k < NSLOT; ++k) if (k == kk1) pl = jpk[k];
                np = __builtin_amdgcn_readlane(pl, lo1) >> 11;
            }
            if (lane == lo) {
#pragma unroll
                for (int k = 0; k < NSLOT; ++k) if (k == kk) jpk[k] = (np << 11) | j0;
            }
            if (lane == 0) rowm[np] = j0;
            j0 = j1;
        }
        __syncthreads();
    }

    // ---- total matched cost: fp32 from coordinates ----
    float sum = 0.0f;
#pragma unroll
    for (int k = 0; k < NSLOT; ++k) {
        int c = lane * NSLOT + k;
        int r = jpk[k] >> 11; if (r < 1) r = 1;
        float4 qq = s1c[r];
        float sx = s2g[3 * c], sy = s2g[3 * c + 1], sz = s2g[3 * c + 2];
        float dx = qq.x - sx, dy = qq.y - sy, dz = qq.z - sz;
        sum += sqrtf(dx * dx + dy * dy + dz * dz);
    }
#pragma unroll
    for (int off = 32; off >= 1; off >>= 1) sum += __shfl_xor(sum, off);
    if (lane == 0) atomicAdd(out, sum * (1.0f / ((float)N * (float)BATCH)));
}

extern "C" void kernel_launch(void* const* d_in, const int* in_sizes, int n_in,
                              void* d_out, int out_size, void* d_ws, size_t ws_size,
                              hipStream_t stream) {
    const float* S1 = (const float*)d_in[0];
    const float* S2 = (const float*)d_in[1];
    float* out = (float*)d_out;

    size_t needD = (size_t)BATCH * N * N * sizeof(unsigned short);   // 16 MB
    size_t needA = (size_t)BATCH * N * 6 * sizeof(int);              // state
    emd_zero_kernel<<<1, 1, 0, stream>>>(out);

    if (ws_size >= needD + needA) {
        unsigned short* D = (unsigned short*)d_ws;
        int* price    = (int*)((char*)d_ws + needD);
        int* owner    = price + BATCH * N;
        int* assigned = owner + BATCH * N;
        int* uarr     = assigned + BATCH * N;
        int* jmin     = uarr + BATCH * N;
        unsigned* bidbuf = (unsigned*)(jmin + BATCH * N);

        emd_init_state<<<(BATCH * N) / 256, 256, 0, stream>>>(price, owner, assigned, bidbuf);
        emd_dist_kernel<<<BATCH * N, 256, 0, stream>>>(S1, S2, D);

        // R10 schedule: gentler ladder, weighted to small-eps phases.
        static const int eps_sched[7]  = {4096, 1024, 256, 64, 16, 4, 1};
        static const int rnds_sched[7] = {12, 12, 16, 20, 28, 40, 72};
        for (int p = 0; p < 7; ++p)
            for (int r = 0; r < rnds_sched[p]; ++r) {
                emd_bid<<<BATCH * 256, 256, 0, stream>>>(D, price, assigned, bidbuf, eps_sched[p]);
                emd_resolve<<<(BATCH * N) / 256, 256, 0, stream>>>(bidbuf, price, owner, assigned);
            }
        emd_project<<<BATCH * 256, 256, 0, stream>>>(D, price, owner, assigned, uarr, jmin);
        emd_claim<<<(BATCH * N) / 256, 256, 0, stream>>>(owner, assigned, jmin);
        emd_jv_kernel<true><<<BATCH, 64, 0, stream>>>(S1, S2, D, price, owner, assigned, uarr, out);
    } else {
        emd_jv_kernel<false><<<BATCH, 64, 0, stream>>>(S1, S2, nullptr, nullptr, nullptr, nullptr, nullptr, out);
    }
}